// Round 3
// baseline (599.325 us; speedup 1.0000x reference)
//
#include <hip/hip_runtime.h>
#include <hip/hip_fp16.h>

// N=50000, K=16, CT=CS=64, S=4, OUT=64
#define CT 64
#define CS 64
#define K_NB 16
#define S_SZ 4
#define OUT_C 64

typedef float vf4 __attribute__((ext_vector_type(4)));  // native vec for nontemporal builtin

// ---------------------------------------------------------------------------
// k1_all: one pass over rows j (block-uniform j, grid-stride).
//   Zh[j][s][o] = fp16( src[j] @ W_lin[s][:,o] + b_lin[s][o] )   (256 cols)
//   t[j][s]  = x[j] @ Wt + bt      (threads 0..3)
//   sl[j][s] = src[j] @ Ws + bs    (threads 4..7)
// W_lin column held in registers (64 VGPR) for the whole block lifetime.
// Row data read via block-uniform float4 loads (broadcast, L1-served after
// first touch) -> no LDS, no barriers.
// ---------------------------------------------------------------------------
__global__ __launch_bounds__(256, 4) void k1_all(
    const float* __restrict__ x, const float* __restrict__ src,
    const float* __restrict__ Wt, const float* __restrict__ bt,
    const float* __restrict__ Ws, const float* __restrict__ bs,
    const float* __restrict__ W_lin, const float* __restrict__ b_lin,
    __half* __restrict__ Zh, float* __restrict__ t_out,
    float* __restrict__ sl_out, int N)
{
    const int col = threadIdx.x;          // col = s*64 + o
    const int s = col >> 6, o = col & 63;
    float w[64];
    #pragma unroll
    for (int c = 0; c < 64; ++c)
        w[c] = W_lin[s * 4096 + (c << 6) + o];   // [s][c][o], coalesced in o
    const float bl = b_lin[col];

    for (int j = blockIdx.x; j < N; j += gridDim.x) {
        const float4* row4 = (const float4*)(src + ((size_t)j << 6));
        float a0 = bl, a1 = 0.f, a2 = 0.f, a3 = 0.f;
        #pragma unroll
        for (int c4 = 0; c4 < 16; ++c4) {
            float4 r = row4[c4];                 // block-uniform broadcast
            a0 = fmaf(r.x, w[c4 * 4 + 0], a0);
            a1 = fmaf(r.y, w[c4 * 4 + 1], a1);
            a2 = fmaf(r.z, w[c4 * 4 + 2], a2);
            a3 = fmaf(r.w, w[c4 * 4 + 3], a3);
        }
        Zh[(size_t)j * 256 + col] = __float2half((a0 + a1) + (a2 + a3));

        if (threadIdx.x < 8) {                   // logits, wave-0 masked lanes
            const int q = threadIdx.x, ss = q & 3;
            const float* rp = (q < 4) ? (x + ((size_t)j << 6))
                                      : (src + ((size_t)j << 6));
            const float* Wp = (q < 4) ? Wt : Ws;
            float acc = (q < 4) ? bt[ss] : bs[ss];
            #pragma unroll
            for (int c = 0; c < 64; ++c)
                acc = fmaf(rp[c], Wp[c * 4 + ss], acc);
            if (q < 4) t_out[(size_t)j * 4 + ss] = acc;
            else       sl_out[(size_t)j * 4 + ss] = acc;
        }
    }
}

// ---------------------------------------------------------------------------
// k2: gather + softmax(S=4) + assignment-weighted mean.
//   out[p][o] = sum_s softmax_s(sl[j]+t[n])[s] * Z[j][s][o] / 4,  j=idx[p]
// Block = one node n (256 threads = 16 p x 16 o-quads). Z is fp16 (25.6 MB
// table) to halve the per-XCD L2-miss re-fetch of the random gather.
// Output stores are nontemporal so the 200 MB write stream doesn't evict Z
// from L2. Stores: 16B/lane fully coalesced (1 KB/wave).
// ---------------------------------------------------------------------------
__global__ __launch_bounds__(256) void k2_out(
    const int* __restrict__ nidx, const float* __restrict__ t_in,
    const float* __restrict__ sl_in, const __half* __restrict__ Zh,
    float* __restrict__ out)
{
    const int T = blockIdx.x * 256 + threadIdx.x;
    const int p = T >> 4;          // (n,k) flat pair
    const int quad = T & 15;       // o = quad*4 .. quad*4+3
    const int n = p >> 4;          // K = 16
    const int j = nidx[p];
    float4 tv = ((const float4*)t_in)[n];    // block-uniform
    float4 sv = ((const float4*)sl_in)[j];
    float l0 = tv.x + sv.x, l1 = tv.y + sv.y;
    float l2 = tv.z + sv.z, l3 = tv.w + sv.w;
    float m = fmaxf(fmaxf(l0, l1), fmaxf(l2, l3));
    float e0 = __expf(l0 - m), e1 = __expf(l1 - m);
    float e2 = __expf(l2 - m), e3 = __expf(l3 - m);
    float inv = 0.25f / (e0 + e1 + e2 + e3);   // softmax norm * (1/size)

    // Zh row = 256 halfs = 128 half2; s-slice stride = 32 half2.
    const __half2* zb = (const __half2*)Zh + (size_t)j * 128 + quad * 2;
    __half2 z0a = zb[0],  z0b = zb[1];
    __half2 z1a = zb[32], z1b = zb[33];
    __half2 z2a = zb[64], z2b = zb[65];
    __half2 z3a = zb[96], z3b = zb[97];
    float2 f0a = __half22float2(z0a), f0b = __half22float2(z0b);
    float2 f1a = __half22float2(z1a), f1b = __half22float2(z1b);
    float2 f2a = __half22float2(z2a), f2b = __half22float2(z2b);
    float2 f3a = __half22float2(z3a), f3b = __half22float2(z3b);

    vf4 o;
    o.x = (e0 * f0a.x + e1 * f1a.x + e2 * f2a.x + e3 * f3a.x) * inv;
    o.y = (e0 * f0a.y + e1 * f1a.y + e2 * f2a.y + e3 * f3a.y) * inv;
    o.z = (e0 * f0b.x + e1 * f1b.x + e2 * f2b.x + e3 * f3b.x) * inv;
    o.w = (e0 * f0b.y + e1 * f1b.y + e2 * f2b.y + e3 * f3b.y) * inv;
    __builtin_nontemporal_store(o, (vf4*)out + (size_t)p * 16 + quad);
}

extern "C" void kernel_launch(void* const* d_in, const int* in_sizes, int n_in,
                              void* d_out, int out_size, void* d_ws, size_t ws_size,
                              hipStream_t stream)
{
    const float* x   = (const float*)d_in[0];
    const float* src = (const float*)d_in[1];
    const int*   idx = (const int*)d_in[2];
    const float* Wt  = (const float*)d_in[3];
    const float* bt  = (const float*)d_in[4];
    const float* Ws  = (const float*)d_in[5];
    const float* bs  = (const float*)d_in[6];
    const float* Wl  = (const float*)d_in[7];
    const float* bl  = (const float*)d_in[8];
    float* out = (float*)d_out;

    const int N = in_sizes[0] / CT;   // 50000

    // Workspace: Zh[N*256] fp16 (25.6 MB) | t[N*4] | sl[N*4] fp32
    __half* Zh = (__half*)d_ws;
    float*  t  = (float*)(Zh + (size_t)N * 256);
    float*  sl = t + (size_t)N * 4;

    hipLaunchKernelGGL(k1_all, dim3(1024), dim3(256), 0, stream,
                       x, src, Wt, bt, Ws, bs, Wl, bl, Zh, t, sl, N);
    hipLaunchKernelGGL(k2_out, dim3(N), dim3(256), 0, stream,
                       idx, t, sl, Zh, out);
}

// Round 4
// 419.623 us; speedup vs baseline: 1.4282x; 1.4282x over previous
//
#include <hip/hip_runtime.h>
#include <hip/hip_fp16.h>

// N=50000, K=16, CT=CS=64, S=4, OUT=64
#define CT 64
#define CS 64
#define K_NB 16
#define S_SZ 4
#define OUT_C 64
#define RPB 16   // rows per k1 block

// ---------------------------------------------------------------------------
// k1_z: per-node transformed messages + assignment logits.
//   Zh[j][s][o] = fp16( src[j] @ W_lin[s][:,o] + b_lin[s][o] )
//   t[j][s]  = x[j] @ Wt + bt ;  sl[j][s] = src[j] @ Ws + bs
// Thread = column col = s*64+o; W_lin column (64 floats) held in VGPRs for
// the whole block. amdgpu_waves_per_eu(4,4) pins the register budget at 128
// VGPRs so the allocator cannot sink the W loads into the row loop (round-3
// failure mode: VGPR_Count=64 proved W was re-loaded per row -> 3.2 GB L1/L2
// traffic). Block owns 16 contiguous rows; row data read via block-uniform
// float4 loads (1 line/instr, L1-served). Logits done once per block by 128
// parallel threads (round-3 had wave-0 serialized per-row -> straggler).
// ---------------------------------------------------------------------------
__global__ __launch_bounds__(256)
__attribute__((amdgpu_waves_per_eu(4, 4)))
void k1_z(
    const float* __restrict__ x, const float* __restrict__ src,
    const float* __restrict__ Wt, const float* __restrict__ bt,
    const float* __restrict__ Ws, const float* __restrict__ bs,
    const float* __restrict__ W_lin, const float* __restrict__ b_lin,
    __half* __restrict__ Zh, float* __restrict__ t_out,
    float* __restrict__ sl_out, int N)
{
    const int col = threadIdx.x;          // col = s*64 + o
    const int s = col >> 6, o = col & 63;
    const int r0 = blockIdx.x * RPB;

    // One-time: this thread's W_lin column into registers (64 VGPRs).
    float w[64];
    #pragma unroll
    for (int c = 0; c < 64; ++c)
        w[c] = W_lin[s * 4096 + (c << 6) + o];   // [s][c][o]: o-coalesced
    const float bl = b_lin[col];

    const int rows = (N - r0 < RPB) ? (N - r0) : RPB;
    for (int r = 0; r < rows; ++r) {
        const float4* row4 = (const float4*)(src + (size_t)(r0 + r) * CS);
        float a0 = bl, a1 = 0.f, a2 = 0.f, a3 = 0.f;
        #pragma unroll
        for (int i = 0; i < 16; ++i) {
            float4 v = row4[i];                  // block-uniform broadcast
            a0 = fmaf(v.x, w[i * 4 + 0], a0);
            a1 = fmaf(v.y, w[i * 4 + 1], a1);
            a2 = fmaf(v.z, w[i * 4 + 2], a2);
            a3 = fmaf(v.w, w[i * 4 + 3], a3);
        }
        Zh[(size_t)(r0 + r) * 256 + col] = __float2half((a0 + a1) + (a2 + a3));
    }

    // Logits: 128 parallel tasks = 16 rows x (2 kinds x 4 s-values).
    if (threadIdx.x < 8 * RPB) {
        const int rl = threadIdx.x >> 3;         // local row
        const int q  = threadIdx.x & 7;
        const int ss = q & 3;
        const int r  = r0 + rl;
        if (r < N) {
            const float4* rp = (const float4*)(((q < 4) ? x : src) + (size_t)r * CT);
            const float*  Wp = (q < 4) ? Wt : Ws;
            float acc = (q < 4) ? bt[ss] : bs[ss];
            #pragma unroll
            for (int i = 0; i < 16; ++i) {
                float4 v = rp[i];
                acc = fmaf(v.x, Wp[(i * 4 + 0) * 4 + ss], acc);
                acc = fmaf(v.y, Wp[(i * 4 + 1) * 4 + ss], acc);
                acc = fmaf(v.z, Wp[(i * 4 + 2) * 4 + ss], acc);
                acc = fmaf(v.w, Wp[(i * 4 + 3) * 4 + ss], acc);
            }
            if (q < 4) t_out[(size_t)r * 4 + ss] = acc;
            else       sl_out[(size_t)r * 4 + ss] = acc;
        }
    }
}

// ---------------------------------------------------------------------------
// k2: gather + softmax(S=4) + assignment-weighted mean.
//   out[p][o] = sum_s softmax_s(sl[j]+t[n])[s] * Z[j][s][o] / 4,  j=idx[p]
// Block = node n (256 threads = 16 k x 16 o-quads). Z fp16 (25.6 MB table)
// halves the random-gather L2-miss traffic vs fp32. Loads are explicit 8 B
// (float2 reinterpreted as 2x __half2); stores plain coalesced float4
// (nontemporal reverted -- round-3 regression suspect).
// ---------------------------------------------------------------------------
__global__ __launch_bounds__(256) void k2_out(
    const int* __restrict__ nidx, const float* __restrict__ t_in,
    const float* __restrict__ sl_in, const __half* __restrict__ Zh,
    float* __restrict__ out)
{
    const int T = blockIdx.x * 256 + threadIdx.x;
    const int p = T >> 4;          // (n,k) flat pair; n == blockIdx.x
    const int quad = T & 15;       // o = quad*4 .. quad*4+3
    const int n = p >> 4;
    const int j = nidx[p];
    float4 tv = ((const float4*)t_in)[n];    // block-uniform
    float4 sv = ((const float4*)sl_in)[j];   // 16-lane broadcast per p
    float l0 = tv.x + sv.x, l1 = tv.y + sv.y;
    float l2 = tv.z + sv.z, l3 = tv.w + sv.w;
    float m = fmaxf(fmaxf(l0, l1), fmaxf(l2, l3));
    float e0 = __expf(l0 - m), e1 = __expf(l1 - m);
    float e2 = __expf(l2 - m), e3 = __expf(l3 - m);
    float inv = 0.25f / (e0 + e1 + e2 + e3);   // softmax norm * (1/size)

    // Zh row = 256 halfs; quad slice = 4 halfs = 8 B = one float2.
    // s-slice stride = 64 halfs = 16 float2.
    const float2* zb = (const float2*)(Zh + (size_t)j * 256) + quad;
    float2 r0 = zb[0], r1 = zb[16], r2 = zb[32], r3 = zb[48];
    const __half2* h0 = (const __half2*)&r0;
    const __half2* h1 = (const __half2*)&r1;
    const __half2* h2 = (const __half2*)&r2;
    const __half2* h3 = (const __half2*)&r3;
    float2 f0a = __half22float2(h0[0]), f0b = __half22float2(h0[1]);
    float2 f1a = __half22float2(h1[0]), f1b = __half22float2(h1[1]);
    float2 f2a = __half22float2(h2[0]), f2b = __half22float2(h2[1]);
    float2 f3a = __half22float2(h3[0]), f3b = __half22float2(h3[1]);

    float4 ov;
    ov.x = (e0 * f0a.x + e1 * f1a.x + e2 * f2a.x + e3 * f3a.x) * inv;
    ov.y = (e0 * f0a.y + e1 * f1a.y + e2 * f2a.y + e3 * f3a.y) * inv;
    ov.z = (e0 * f0b.x + e1 * f1b.x + e2 * f2b.x + e3 * f3b.x) * inv;
    ov.w = (e0 * f0b.y + e1 * f1b.y + e2 * f2b.y + e3 * f3b.y) * inv;
    ((float4*)out)[(size_t)p * 16 + quad] = ov;
}

extern "C" void kernel_launch(void* const* d_in, const int* in_sizes, int n_in,
                              void* d_out, int out_size, void* d_ws, size_t ws_size,
                              hipStream_t stream)
{
    const float* x   = (const float*)d_in[0];
    const float* src = (const float*)d_in[1];
    const int*   idx = (const int*)d_in[2];
    const float* Wt  = (const float*)d_in[3];
    const float* bt  = (const float*)d_in[4];
    const float* Ws  = (const float*)d_in[5];
    const float* bs  = (const float*)d_in[6];
    const float* Wl  = (const float*)d_in[7];
    const float* bl  = (const float*)d_in[8];
    float* out = (float*)d_out;

    const int N = in_sizes[0] / CT;   // 50000

    // Workspace: Zh[N*256] fp16 (25.6 MB) | t[N*4] | sl[N*4] fp32
    __half* Zh = (__half*)d_ws;
    float*  t  = (float*)(Zh + (size_t)N * 256);
    float*  sl = t + (size_t)N * 4;

    hipLaunchKernelGGL(k1_z, dim3((N + RPB - 1) / RPB), dim3(256), 0, stream,
                       x, src, Wt, bt, Ws, bs, Wl, bl, Zh, t, sl, N);
    hipLaunchKernelGGL(k2_out, dim3(N), dim3(256), 0, stream,
                       idx, t, sl, Zh, out);
}